// Round 4
// baseline (800.287 us; speedup 1.0000x reference)
//
#include <hip/hip_runtime.h>
#include <hip/hip_cooperative_groups.h>
#include <hip/hip_bf16.h>
#include <hip/hip_fp8.h>
#include <cstdint>

namespace cg = cooperative_groups;

// ---------------------------------------------------------------------------
// DeepFM forward, MI355X — single cooperative megakernel (R4).
// Phases (grid.sync between):
//   P0: W1..W3 f32->fp8 transpose + embedding gather/FM partials (no atomics)
//   P1: GEMM1 (512->2048)  2 tiles/block      [R3-verified fp8 MX GEMM body]
//   P2: GEMM2 (2048->1024) 1 tile/block
//   P3: GEMM3 (1024->512)  blocks<512; block 1023 reduces FM scalar S
//   P4: L4 dot (512->1) + sigmoid
// Rationale: R1-R3 totals show ~100 us of fixed inter-dispatch overhead
// (sum of kernel durs ~110 us vs dur_us 218). One dispatch removes it.
// ---------------------------------------------------------------------------

typedef float f32x4 __attribute__((ext_vector_type(4)));
typedef int i32x4 __attribute__((ext_vector_type(4)));
typedef int i32x8 __attribute__((ext_vector_type(8)));

#define GLOAD16(gptr, lptr)                                                \
  __builtin_amdgcn_global_load_lds(                                        \
      (const __attribute__((address_space(1))) void*)(gptr),               \
      (__attribute__((address_space(3))) void*)(lptr), 16, 0, 0)

__device__ inline uint8_t f2fp8(float v) {
  __hip_fp8_e4m3 t(v);
  return t.__x;
}
__device__ inline float fp82f(uint8_t b) {
  __hip_fp8_e4m3 t;
  t.__x = b;
  return (float)t;
}

// ---------------- workspace layout (bytes) ---------------------------------
static constexpr size_t OFF_LIN  = 0;                          // 16384 f32
static constexpr size_t OFF_PART = 65536;                      // 1024 f32
static constexpr size_t OFF_S    = 81920;                      // 1 f32
static constexpr size_t OFF_EMB  = 131072;                     // B*512 fp8
static constexpr size_t OFF_H1   = OFF_EMB + 8388608ull;       // B*2048 fp8
static constexpr size_t OFF_H2   = OFF_H1 + 33554432ull;       // B*1024 fp8
static constexpr size_t OFF_H3   = OFF_H2 + 16777216ull;       // B*512 fp8
static constexpr size_t OFF_W1T  = OFF_H3 + 8388608ull;        // 2048*512 fp8
static constexpr size_t OFF_W2T  = OFF_W1T + 1048576ull;       // 1024*2048 fp8
static constexpr size_t OFF_W3T  = OFF_W2T + 2097152ull;       // 512*1024 fp8

struct KArgs {
  const float *x, *bias, *fc, *emb;
  const float *W1, *b1, *W2, *b2, *W3, *b3, *W4, *b4;
  float* out;
  char* ws;
};

// ---------------- P0a: one 32x32 transpose tile, f32 -> fp8 ----------------
__device__ void do_transpose(const float* __restrict__ W,
                             uint8_t* __restrict__ WT, int K, int N, int bx,
                             int by, float* tile /*32x33*/) {
  int tid = threadIdx.x;
  int tx = tid & 31, ty = tid >> 5;
  int n0 = bx * 32, k0 = by * 32;
#pragma unroll
  for (int i = ty; i < 32; i += 8)
    tile[i * 33 + tx] = W[(size_t)(k0 + i) * N + n0 + tx];
  __syncthreads();
#pragma unroll
  for (int i = ty; i < 32; i += 8)
    WT[(size_t)(n0 + i) * K + k0 + tx] = f2fp8(tile[tx * 33 + i]);
  __syncthreads();
}

// ---------------- P0b: gather 16 samples/block + FM partial ----------------
__device__ void do_gather(const KArgs& a, uint8_t* ebf, float* lin,
                          float* part, float* pt /*LDS float[4]*/) {
  int tid = threadIdx.x;
  int wv = tid >> 6, lane = tid & 63;
  int f = lane >> 4;
  float wsum = 0.f;
  int b0 = blockIdx.x * 16 + wv * 4;
#pragma unroll
  for (int it = 0; it < 4; ++it) {
    int b = b0 + it;
    int idx = (int)a.x[b * 4 + f];             // raw index (NO offset) for emb
    const float* row = a.emb + (size_t)idx * 128 + (lane & 15) * 8;
    float4 v0 = ((const float4*)row)[0];
    float4 v1 = ((const float4*)row)[1];
    float s = v0.x + v0.y + v0.z + v0.w + v1.x + v1.y + v1.z + v1.w;
    float q = v0.x * v0.x + v0.y * v0.y + v0.z * v0.z + v0.w * v0.w +
              v1.x * v1.x + v1.y * v1.y + v1.z * v1.z + v1.w * v1.w;

    uint64_t pk = 0;
    float vv[8] = {v0.x, v0.y, v0.z, v0.w, v1.x, v1.y, v1.z, v1.w};
#pragma unroll
    for (int j = 0; j < 8; ++j) pk |= (uint64_t)f2fp8(vv[j]) << (8 * j);
    *(uint64_t*)(ebf + (size_t)b * 512 + lane * 8) = pk;

    float lp = 0.f;
    if ((lane & 15) == 0) {                    // fc lookup USES offsets
      int off = (f == 1) ? 31360 : (f == 2) ? 38167 : (f == 3) ? 38185 : 0;
      lp = a.fc[idx + off];
    }
#pragma unroll
    for (int m = 32; m; m >>= 1) {
      s += __shfl_xor(s, m);
      q += __shfl_xor(q, m);
      lp += __shfl_xor(lp, m);
    }
    if (lane == 0) {
      lin[b] = lp;
      wsum += s * s - q;
    }
  }
  if (lane == 0) pt[wv] = wsum;
  __syncthreads();
  if (tid == 0) part[blockIdx.x] = pt[0] + pt[1] + pt[2] + pt[3];
}

// ---------------- GEMM tile: C = relu(A*B + bias), B given as B^T ----------
// R3-verified: 128x128 tile, BK=128, 4 waves of 64x64, global_load_lds
// width=16, XOR-chunk swizzle (conflict math verified R2/R3), MX-fp8 MFMA
// 16x16x128 with unit scales (E8M0 0x7F).
__device__ void do_gemm(const uint8_t* __restrict__ A,
                        const uint8_t* __restrict__ BT,
                        const float* __restrict__ bias,
                        uint8_t* __restrict__ C, int K, int N, int bx, int by,
                        uint8_t (*As)[128], uint8_t (*Bs)[128]) {
  int tid = threadIdx.x;
  int wv = tid >> 6, lane = tid & 63;
  int m0 = by * 128, n0 = bx * 128;
  int mw = (wv >> 1) * 64, nw = (wv & 1) * 64;
  int ml = lane & 15, kg = lane >> 4;
  int srow = lane >> 3;
  int scol = ((lane & 7) ^ srow) * 16;
  int p0 = ((2 * kg) ^ (ml & 7)) * 16;
  int p1 = ((2 * kg + 1) ^ (ml & 7)) * 16;

  f32x4 acc[4][4];
#pragma unroll
  for (int i = 0; i < 4; ++i)
#pragma unroll
    for (int j = 0; j < 4; ++j) acc[i][j] = (f32x4){0.f, 0.f, 0.f, 0.f};

  for (int kt = 0; kt < K; kt += 128) {
#pragma unroll
    for (int r = 0; r < 4; ++r) {
      int g = r * 4 + wv;
      const uint8_t* ga = A + (size_t)(m0 + 8 * g + srow) * K + kt + scol;
      GLOAD16(ga, &As[8 * g][0]);
      const uint8_t* gb = BT + (size_t)(n0 + 8 * g + srow) * K + kt + scol;
      GLOAD16(gb, &Bs[8 * g][0]);
    }
    __syncthreads();

    i32x8 af[4], bfr[4];
#pragma unroll
    for (int t = 0; t < 4; ++t) {
      int ra = mw + t * 16 + ml;
      i32x4 lo = *(const i32x4*)&As[ra][p0];
      i32x4 hi = *(const i32x4*)&As[ra][p1];
      af[t] = __builtin_shufflevector(lo, hi, 0, 1, 2, 3, 4, 5, 6, 7);
      int rb = nw + t * 16 + ml;
      lo = *(const i32x4*)&Bs[rb][p0];
      hi = *(const i32x4*)&Bs[rb][p1];
      bfr[t] = __builtin_shufflevector(lo, hi, 0, 1, 2, 3, 4, 5, 6, 7);
    }
#pragma unroll
    for (int mt = 0; mt < 4; ++mt)
#pragma unroll
      for (int nt = 0; nt < 4; ++nt)
        acc[mt][nt] = __builtin_amdgcn_mfma_scale_f32_16x16x128_f8f6f4(
            af[mt], bfr[nt], acc[mt][nt], 0, 0, 0, 0x7F7F7F7F, 0, 0x7F7F7F7F);
    __syncthreads();
  }

  // C/D layout: col=lane&15, row=(lane>>4)*4+reg (shape-determined)
  int rbase = kg * 4;
#pragma unroll
  for (int nt = 0; nt < 4; ++nt) {
    int col = n0 + nw + nt * 16 + ml;
    float bv = bias[col];
#pragma unroll
    for (int mt = 0; mt < 4; ++mt) {
      int row = m0 + mw + mt * 16 + rbase;
#pragma unroll
      for (int r = 0; r < 4; ++r) {
        float v = acc[mt][nt][r] + bv;
        v = v > 0.f ? v : 0.f;
        C[(size_t)(row + r) * N + col] = f2fp8(v);
      }
    }
  }
}

// ---------------- P4: L4 dot + sigmoid, 16 samples/block -------------------
__device__ void do_out(const KArgs& a, const uint8_t* h3, const float* lin,
                       const float* S, float* out) {
  int tid = threadIdx.x;
  int wv = tid >> 6, lane = tid & 63;
  const float* wp = a.W4 + lane * 8;
  float4 w0 = ((const float4*)wp)[0];
  float4 w1 = ((const float4*)wp)[1];
  float wf[8] = {w0.x, w0.y, w0.z, w0.w, w1.x, w1.y, w1.z, w1.w};
  float base = a.b4[0] + a.bias[0] + 0.5f * S[0];
  int b0 = blockIdx.x * 16 + wv * 4;
#pragma unroll
  for (int it = 0; it < 4; ++it) {
    int b = b0 + it;
    uint64_t pk = *(const uint64_t*)(h3 + (size_t)b * 512 + lane * 8);
    float acc = 0.f;
#pragma unroll
    for (int j = 0; j < 8; ++j)
      acc += fp82f((uint8_t)(pk >> (8 * j))) * wf[j];
#pragma unroll
    for (int m = 32; m; m >>= 1) acc += __shfl_xor(acc, m);
    if (lane == 0) {
      float z = acc + base + lin[b];
      out[b] = 1.f / (1.f + expf(-z));
    }
  }
}

// ---------------- megakernel ----------------------------------------------
__global__ __launch_bounds__(256, 4) void deepfm_mega(KArgs a) {
  __shared__ __align__(16) uint8_t smem[32768];
  float* lin    = (float*)(a.ws + OFF_LIN);
  float* part   = (float*)(a.ws + OFF_PART);
  float* Sp     = (float*)(a.ws + OFF_S);
  uint8_t* EMBb = (uint8_t*)(a.ws + OFF_EMB);
  uint8_t* H1   = (uint8_t*)(a.ws + OFF_H1);
  uint8_t* H2   = (uint8_t*)(a.ws + OFF_H2);
  uint8_t* H3   = (uint8_t*)(a.ws + OFF_H3);
  uint8_t* W1T  = (uint8_t*)(a.ws + OFF_W1T);
  uint8_t* W2T  = (uint8_t*)(a.ws + OFF_W2T);
  uint8_t* W3T  = (uint8_t*)(a.ws + OFF_W3T);

  int b = blockIdx.x;
  cg::grid_group grid = cg::this_grid();

  // ---- P0: weight transposes (1024/2048/512 tiles) + gather ----
  float* ttile = (float*)smem;
  do_transpose(a.W1, W1T, 512, 2048, b & 63, b >> 6, ttile);
  do_transpose(a.W2, W2T, 2048, 1024, b & 31, b >> 5, ttile);
  {
    int t = b + 1024;
    do_transpose(a.W2, W2T, 2048, 1024, t & 31, t >> 5, ttile);
  }
  if (b < 512) do_transpose(a.W3, W3T, 1024, 512, b & 15, b >> 4, ttile);
  do_gather(a, EMBb, lin, part, (float*)(smem + 8192));
  grid.sync();

  // ---- P1: GEMM1 (M=16384,N=2048,K=512), 2 tiles/block ----
  uint8_t(*As)[128] = (uint8_t(*)[128])smem;
  uint8_t(*Bs)[128] = (uint8_t(*)[128])(smem + 16384);
  do_gemm(EMBb, W1T, a.b1, H1, 512, 2048, b >> 7, b & 127, As, Bs);
  do_gemm(EMBb, W1T, a.b1, H1, 512, 2048, (b >> 7) + 8, b & 127, As, Bs);
  grid.sync();

  // ---- P2: GEMM2 (M=16384,N=1024,K=2048), 1 tile/block ----
  do_gemm(H1, W2T, a.b2, H2, 2048, 1024, b >> 7, b & 127, As, Bs);
  grid.sync();

  // ---- P3: GEMM3 (M=16384,N=512,K=1024) on blocks<512; S-reduce on 1023 --
  if (b < 512) {
    do_gemm(H2, W3T, a.b3, H3, 1024, 512, b >> 7, b & 127, As, Bs);
  } else if (b == 1023) {
    int tid = threadIdx.x;
    float v = 0.f;
    for (int i = tid; i < 1024; i += 256) v += part[i];
#pragma unroll
    for (int m = 32; m; m >>= 1) v += __shfl_xor(v, m);
    float* ps = (float*)smem;
    if ((tid & 63) == 0) ps[tid >> 6] = v;
    __syncthreads();
    if (tid == 0) Sp[0] = ps[0] + ps[1] + ps[2] + ps[3];
  }
  grid.sync();

  // ---- P4: output ----
  do_out(a, H3, lin, Sp, a.out);
}

// ---------------------------------------------------------------------------
extern "C" void kernel_launch(void* const* d_in, const int* in_sizes, int n_in,
                              void* d_out, int out_size, void* d_ws,
                              size_t ws_size, hipStream_t stream) {
  KArgs ka;
  ka.x    = (const float*)d_in[0];
  ka.bias = (const float*)d_in[1];
  ka.fc   = (const float*)d_in[2];
  ka.emb  = (const float*)d_in[3];
  ka.W1   = (const float*)d_in[4];
  ka.b1   = (const float*)d_in[5];
  ka.W2   = (const float*)d_in[6];
  ka.b2   = (const float*)d_in[7];
  ka.W3   = (const float*)d_in[8];
  ka.b3   = (const float*)d_in[9];
  ka.W4   = (const float*)d_in[10];
  ka.b4   = (const float*)d_in[11];
  ka.out  = (float*)d_out;
  ka.ws   = (char*)d_ws;

  void* params[] = {(void*)&ka};
  hipLaunchCooperativeKernel((void*)deepfm_mega, dim3(1024), dim3(256), params,
                             0, stream);
}

// Round 5
// 220.889 us; speedup vs baseline: 3.6230x; 3.6230x over previous
//
#include <hip/hip_runtime.h>
#include <cstdint>

// ---------------------------------------------------------------------------
// DeepFM forward, MI355X (R5).
//   Stage 1: prep  — W1..W3 f32 (K,N) -> fp4-e2m1 W^T (N,K), pre-scaled 2^7
//   Stage 2: gather — embed_x fp4 (B,512 packed), per-sample lin, FM partials
//   Stage 3: reduce — batch-global FM scalar S (fp32, reference quirk)
//   Stage 4: 3x MX-fp4 MFMA GEMM (16x16x128 f8f6f4, fmt=4), bias+ReLU
//   Stage 5: L4 dot (512->1, fp32 weights) + sigmoid(fm + mlp)
//
// R5 changes vs R3 (R4 megakernel reverted — VGPR cap 64 caused 260 MB of
// scratch spills; single-dispatch run also proved the ~100 us non-kernel time
// is harness-fixed, not per-node):
//  - GEMMs: fp8 -> fp4 e2m1, both operands. MFMA rate 2x (m59), staging and
//    LDS traffic 2x lower. Weights pre-scaled by 2^7 before quantization
//    (fp4 min normal 0.5 >> |W|max 0.044), MX B-scale = 2^-7 (E8M0 0x78).
//  - LDS rows 64 B, chunk swizzle c ^= row&3 (analyzed: exact 8-beat min).
//  - Epilogue packs col-pairs via __shfl_xor(1); even lanes store bytes.
//  - Consistency argument: identical k-permutation on A and B packing leaves
//    the dot product invariant, so nibble/chunk order is provably safe.
//  - 3 transpose kernels merged into 1 (8 nodes total).
// ---------------------------------------------------------------------------

typedef float f32x4 __attribute__((ext_vector_type(4)));
typedef int i32x4 __attribute__((ext_vector_type(4)));
typedef int i32x8 __attribute__((ext_vector_type(8)));

#define GLOAD16(gptr, lptr)                                                \
  __builtin_amdgcn_global_load_lds(                                        \
      (const __attribute__((address_space(1))) void*)(gptr),               \
      (__attribute__((address_space(3))) void*)(lptr), 16, 0, 0)

// fp4 e2m1 encode (RNE boundaries; magnitudes 0,.5,1,1.5,2,3,4,6)
__device__ inline uint32_t f2fp4(float v) {
  uint32_t s = (__float_as_uint(v) >> 31) << 3;
  float a = fabsf(v);
  uint32_t m;
  if (a < 0.25f) m = 0;
  else if (a < 0.75f) m = 1;
  else if (a < 1.25f) m = 2;
  else if (a < 1.75f) m = 3;
  else if (a < 2.5f)  m = 4;
  else if (a < 3.5f)  m = 5;
  else if (a < 5.0f)  m = 6;
  else m = 7;
  return s | m;
}
__device__ inline float fp42f(uint32_t c) {
  const float mag[8] = {0.f, 0.5f, 1.f, 1.5f, 2.f, 3.f, 4.f, 6.f};
  float v = mag[c & 7];
  return (c & 8) ? -v : v;
}

// ---------------- workspace layout (bytes) ---------------------------------
static constexpr size_t OFF_LIN  = 0;                          // 16384 f32
static constexpr size_t OFF_PART = 65536;                      // 4096 f32
static constexpr size_t OFF_S    = 81920;                      // 1 f32
static constexpr size_t OFF_EMB  = 131072;                     // B*512 fp4 = 4 MB
static constexpr size_t OFF_H1   = OFF_EMB + 4194304ull;       // B*2048 fp4 = 16 MB
static constexpr size_t OFF_H2   = OFF_H1 + 16777216ull;       // B*1024 fp4 = 8 MB
static constexpr size_t OFF_H3   = OFF_H2 + 8388608ull;        // B*512 fp4 = 4 MB
static constexpr size_t OFF_W1T  = OFF_H3 + 4194304ull;        // 2048*512/2
static constexpr size_t OFF_W2T  = OFF_W1T + 524288ull;        // 1024*2048/2
static constexpr size_t OFF_W3T  = OFF_W2T + 1048576ull;       // 512*1024/2

// ---------------- Stage 1: all 3 transposes, f32 -> fp4 (x128 pre-scale) ---
__global__ void transpose_cvt_all(const float* __restrict__ W1,
                                  const float* __restrict__ W2,
                                  const float* __restrict__ W3,
                                  uint8_t* __restrict__ W1T,
                                  uint8_t* __restrict__ W2T,
                                  uint8_t* __restrict__ W3T) {
  __shared__ float tile[32][33];
  int b = blockIdx.x;
  const float* W;
  uint8_t* WT;
  int K, N, bx, by;
  if (b < 1024) {        // W1: K=512, N=2048 -> 64 x 16 tiles
    W = W1; WT = W1T; K = 512; N = 2048; bx = b & 63; by = b >> 6;
  } else if (b < 3072) { // W2: K=2048, N=1024 -> 32 x 64 tiles
    int t = b - 1024;
    W = W2; WT = W2T; K = 2048; N = 1024; bx = t & 31; by = t >> 5;
  } else {               // W3: K=1024, N=512 -> 16 x 32 tiles
    int t = b - 3072;
    W = W3; WT = W3T; K = 1024; N = 512; bx = t & 15; by = t >> 4;
  }
  int tx = threadIdx.x, ty = threadIdx.y;
  int n0 = bx * 32, k0 = by * 32;
#pragma unroll
  for (int i = ty; i < 32; i += 8)
    tile[i][tx] = W[(size_t)(k0 + i) * N + n0 + tx];
  __syncthreads();
  if (tx < 16) {
#pragma unroll
    for (int i = ty; i < 32; i += 8) {
      // WT row n0+i, k-pair (k0+2tx, k0+2tx+1); pre-scale 2^7 (MX descale 2^-7)
      uint32_t lo = f2fp4(tile[2 * tx][i] * 128.f);
      uint32_t hi = f2fp4(tile[2 * tx + 1][i] * 128.f);
      WT[(size_t)(n0 + i) * (K >> 1) + (k0 >> 1) + tx] = (uint8_t)(lo | (hi << 4));
    }
  }
}

// ---------------- Stage 2: gather + FM ------------------------------------
// One wave per sample. Lane l: field f = l>>4, 8 dims at (l&15)*8.
__global__ void gather_fm(const float* __restrict__ x,
                          const float* __restrict__ fc,
                          const float* __restrict__ emb,
                          uint8_t* __restrict__ ebf,
                          float* __restrict__ lin,
                          float* __restrict__ partials) {
  int tid = threadIdx.x;
  int wv = tid >> 6, lane = tid & 63;
  int b = blockIdx.x * 4 + wv;
  int f = lane >> 4;
  int idx = (int)x[b * 4 + f];                 // raw index (NO offset) for emb
  const float* row = emb + (size_t)idx * 128 + (lane & 15) * 8;
  float4 v0 = ((const float4*)row)[0];
  float4 v1 = ((const float4*)row)[1];
  float s = v0.x + v0.y + v0.z + v0.w + v1.x + v1.y + v1.z + v1.w;
  float q = v0.x * v0.x + v0.y * v0.y + v0.z * v0.z + v0.w * v0.w +
            v1.x * v1.x + v1.y * v1.y + v1.z * v1.z + v1.w * v1.w;

  float vv[8] = {v0.x, v0.y, v0.z, v0.w, v1.x, v1.y, v1.z, v1.w};
  uint32_t pk = 0;
#pragma unroll
  for (int j = 0; j < 8; ++j) pk |= f2fp4(vv[j]) << (4 * j);
  *(uint32_t*)(ebf + (size_t)b * 256 + lane * 4) = pk;   // 4 B/lane coalesced

  float lp = 0.f;
  if ((lane & 15) == 0) {                      // fc lookup USES offsets
    int off = (f == 1) ? 31360 : (f == 2) ? 38167 : (f == 3) ? 38185 : 0;
    lp = fc[idx + off];
  }
#pragma unroll
  for (int m = 32; m; m >>= 1) {
    s += __shfl_xor(s, m);
    q += __shfl_xor(q, m);
    lp += __shfl_xor(lp, m);
  }
  __shared__ float pt[4];
  if (lane == 0) {
    lin[b] = lp;
    pt[wv] = s * s - q;                        // per-sample FM term
  }
  __syncthreads();
  if (tid == 0) partials[blockIdx.x] = pt[0] + pt[1] + pt[2] + pt[3];
}

// ---------------- Stage 3: reduce FM partials -> scalar S ------------------
__global__ void reduce_partials(const float* __restrict__ p,
                                float* __restrict__ S) {
  int tid = threadIdx.x;
  float v = 0.f;
  for (int i = tid; i < 4096; i += 256) v += p[i];
#pragma unroll
  for (int m = 32; m; m >>= 1) v += __shfl_xor(v, m);
  __shared__ float ps[4];
  if ((tid & 63) == 0) ps[tid >> 6] = v;
  __syncthreads();
  if (tid == 0) S[0] = ps[0] + ps[1] + ps[2] + ps[3];
}

// ---------------- Stage 4: MX-fp4 GEMM, C = relu(A*B + bias), B as B^T -----
// 128x128 tile, BK=128 elems (64 B/row), 4 waves of 64x64, global_load_lds
// width=16, chunk swizzle c^=row&3 (8-beat-min optimal), MFMA 16x16x128
// f8f6f4 fmt=4 (fp4), scale_a=1 (0x7F), scale_b=2^-7 (0x78). K,N in elements;
// A,BT,C fp4-packed with strides K/2, K/2, N/2 bytes.
__global__ __launch_bounds__(256) void gemm_fp4_relu(
    const uint8_t* __restrict__ A, const uint8_t* __restrict__ BT,
    const float* __restrict__ bias, uint8_t* __restrict__ C, int K, int N) {
  __shared__ __align__(16) uint8_t As[128][64];
  __shared__ __align__(16) uint8_t Bs[128][64];
  int tid = threadIdx.x;
  int wv = tid >> 6, lane = tid & 63;
  int m0 = blockIdx.y * 128, n0 = blockIdx.x * 128;
  int mw = (wv >> 1) * 64, nw = (wv & 1) * 64;
  int ml = lane & 15, kg = lane >> 4;
  int Kb = K >> 1;
  int srow = lane >> 2;                        // staging row within 16-row grp
  int sc = ((lane & 3) ^ (srow & 3)) * 16;     // swizzled source chunk
  int p = (kg ^ (ml & 3)) * 16;                // fragment read byte offset

  f32x4 acc[4][4];
#pragma unroll
  for (int i = 0; i < 4; ++i)
#pragma unroll
    for (int j = 0; j < 4; ++j) acc[i][j] = (f32x4){0.f, 0.f, 0.f, 0.f};

  for (int kt = 0; kt < Kb; kt += 64) {        // 64 B = 128 k-elems
#pragma unroll
    for (int r = 0; r < 2; ++r) {
      int g = r * 4 + wv;                      // 16-row group 0..7
      const uint8_t* ga = A + (size_t)(m0 + 16 * g + srow) * Kb + kt + sc;
      GLOAD16(ga, &As[16 * g][0]);
      const uint8_t* gb = BT + (size_t)(n0 + 16 * g + srow) * Kb + kt + sc;
      GLOAD16(gb, &Bs[16 * g][0]);
    }
    __syncthreads();

    i32x8 af[4], bfr[4];
    i32x4 z = (i32x4){0, 0, 0, 0};
#pragma unroll
    for (int t = 0; t < 4; ++t) {
      i32x4 va = *(const i32x4*)&As[mw + t * 16 + ml][p];
      af[t] = __builtin_shufflevector(va, z, 0, 1, 2, 3, 4, 5, 6, 7);
      i32x4 vb = *(const i32x4*)&Bs[nw + t * 16 + ml][p];
      bfr[t] = __builtin_shufflevector(vb, z, 0, 1, 2, 3, 4, 5, 6, 7);
    }
#pragma unroll
    for (int mt = 0; mt < 4; ++mt)
#pragma unroll
      for (int nt = 0; nt < 4; ++nt)
        acc[mt][nt] = __builtin_amdgcn_mfma_scale_f32_16x16x128_f8f6f4(
            af[mt], bfr[nt], acc[mt][nt],
            /*cbsz=fp4*/ 4, /*blgp=fp4*/ 4,
            0, 0x7F7F7F7F,      // scale_a = 1.0
            0, 0x78787878);     // scale_b = 2^-7 (undo W pre-scale)
    __syncthreads();
  }

  // Epilogue: C/D layout col=lane&15, row=(lane>>4)*4+reg. Pack col pairs
  // (lanes ml, ml^1 hold adjacent cols) via shfl; even lanes store bytes.
  int rbase = kg * 4;
#pragma unroll
  for (int nt = 0; nt < 4; ++nt) {
    int col = n0 + nw + nt * 16 + ml;
    float bv = bias[col];
#pragma unroll
    for (int mt = 0; mt < 4; ++mt) {
      int row = m0 + mw + mt * 16 + rbase;
#pragma unroll
      for (int r = 0; r < 4; ++r) {
        float v = acc[mt][nt][r] + bv;
        v = v > 0.f ? v : 0.f;
        uint32_t code = f2fp4(v);
        uint32_t up = (uint32_t)__shfl_xor((int)code, 1);
        if (!(ml & 1))
          C[(size_t)(row + r) * (N >> 1) + (col >> 1)] =
              (uint8_t)(code | (up << 4));
      }
    }
  }
}

// ---------------- Stage 5: L4 (512->1) + sigmoid ---------------------------
__global__ void mlp_out_sigmoid(const uint8_t* __restrict__ h3,
                                const float* __restrict__ W4,
                                const float* __restrict__ b4,
                                const float* __restrict__ bias,
                                const float* __restrict__ lin,
                                const float* __restrict__ S,
                                float* __restrict__ out) {
  int tid = threadIdx.x;
  int wv = tid >> 6, lane = tid & 63;
  int b = blockIdx.x * 4 + wv;
  uint32_t pk = *(const uint32_t*)(h3 + (size_t)b * 256 + lane * 4);
  const float* wp = W4 + lane * 8;
  float4 w0 = ((const float4*)wp)[0];
  float4 w1 = ((const float4*)wp)[1];
  float wf[8] = {w0.x, w0.y, w0.z, w0.w, w1.x, w1.y, w1.z, w1.w};
  float acc = 0.f;
#pragma unroll
  for (int j = 0; j < 8; ++j)
    acc += fp42f((pk >> (4 * j)) & 15) * wf[j];
#pragma unroll
  for (int m = 32; m; m >>= 1) acc += __shfl_xor(acc, m);
  if (lane == 0) {
    float z = acc + b4[0] + bias[0] + lin[b] + 0.5f * S[0];
    out[b] = 1.f / (1.f + expf(-z));
  }
}

// ---------------------------------------------------------------------------
extern "C" void kernel_launch(void* const* d_in, const int* in_sizes, int n_in,
                              void* d_out, int out_size, void* d_ws,
                              size_t ws_size, hipStream_t stream) {
  const float* x    = (const float*)d_in[0];
  const float* bias = (const float*)d_in[1];
  const float* fc   = (const float*)d_in[2];
  const float* emb  = (const float*)d_in[3];
  const float* W1   = (const float*)d_in[4];
  const float* b1   = (const float*)d_in[5];
  const float* W2   = (const float*)d_in[6];
  const float* b2   = (const float*)d_in[7];
  const float* W3   = (const float*)d_in[8];
  const float* b3   = (const float*)d_in[9];
  const float* W4   = (const float*)d_in[10];
  const float* b4   = (const float*)d_in[11];
  float* out = (float*)d_out;

  char* ws = (char*)d_ws;
  float* lin    = (float*)(ws + OFF_LIN);
  float* part   = (float*)(ws + OFF_PART);
  float* Sp     = (float*)(ws + OFF_S);
  uint8_t* EMBb = (uint8_t*)(ws + OFF_EMB);
  uint8_t* H1   = (uint8_t*)(ws + OFF_H1);
  uint8_t* H2   = (uint8_t*)(ws + OFF_H2);
  uint8_t* H3   = (uint8_t*)(ws + OFF_H3);
  uint8_t* W1T  = (uint8_t*)(ws + OFF_W1T);
  uint8_t* W2T  = (uint8_t*)(ws + OFF_W2T);
  uint8_t* W3T  = (uint8_t*)(ws + OFF_W3T);

  transpose_cvt_all<<<3584, dim3(32, 8), 0, stream>>>(W1, W2, W3, W1T, W2T,
                                                      W3T);
  gather_fm<<<4096, 256, 0, stream>>>(x, fc, emb, EMBb, lin, part);
  reduce_partials<<<1, 256, 0, stream>>>(part, Sp);

  gemm_fp4_relu<<<dim3(16, 128), 256, 0, stream>>>(EMBb, W1T, b1, H1, 512, 2048);
  gemm_fp4_relu<<<dim3(8, 128), 256, 0, stream>>>(H1, W2T, b2, H2, 2048, 1024);
  gemm_fp4_relu<<<dim3(4, 128), 256, 0, stream>>>(H2, W3T, b3, H3, 1024, 512);

  mlp_out_sigmoid<<<4096, 256, 0, stream>>>(H3, W4, b4, bias, lin, Sp, out);
}

// Round 6
// 206.842 us; speedup vs baseline: 3.8691x; 1.0679x over previous
//
#include <hip/hip_runtime.h>
#include <cstdint>

// ---------------------------------------------------------------------------
// DeepFM forward, MI355X (R6).
//   Stage 1: prep  — W1..W3 f32 (K,N) -> fp4-e2m1 W^T (N,K), pre-scaled 2^7
//   Stage 2: gather — embed_x fp4 (B,512 packed), per-sample lin, FM partials
//   Stage 3: reduce — batch-global FM scalar S (fp32, reference quirk)
//   Stage 4: 3x MX-fp4 MFMA GEMM (16x16x128 f8f6f4 fmt=4), bias+ReLU
//   Stage 5: L4 dot (512->1, fp32 weights) + sigmoid(fm + mlp)
//
// R6 changes vs R5 (R5 was traffic-halved but latency-bound: ~1800 cyc per
// k-iteration vs ~190 cyc work — barrier drain of HBM-latency staging):
//  - XCD-aware block swizzle: blocks sharing an A M-strip get the same
//    bid%8 (same XCD) -> A-strip L2-resident -> staging latency ~900->~200.
//  - BK 128->256 elems (128 B LDS rows, 32 KB total): half the barriers,
//    32 MFMA/wave per barrier. Staging swizzle = R3-verified 128 B-row form.
// ---------------------------------------------------------------------------

typedef float f32x4 __attribute__((ext_vector_type(4)));
typedef int i32x4 __attribute__((ext_vector_type(4)));
typedef int i32x8 __attribute__((ext_vector_type(8)));

#define GLOAD16(gptr, lptr)                                                \
  __builtin_amdgcn_global_load_lds(                                        \
      (const __attribute__((address_space(1))) void*)(gptr),               \
      (__attribute__((address_space(3))) void*)(lptr), 16, 0, 0)

// fp4 e2m1 encode (RNE boundaries; magnitudes 0,.5,1,1.5,2,3,4,6)
__device__ inline uint32_t f2fp4(float v) {
  uint32_t s = (__float_as_uint(v) >> 31) << 3;
  float a = fabsf(v);
  uint32_t m;
  if (a < 0.25f) m = 0;
  else if (a < 0.75f) m = 1;
  else if (a < 1.25f) m = 2;
  else if (a < 1.75f) m = 3;
  else if (a < 2.5f)  m = 4;
  else if (a < 3.5f)  m = 5;
  else if (a < 5.0f)  m = 6;
  else m = 7;
  return s | m;
}
__device__ inline float fp42f(uint32_t c) {
  const float mag[8] = {0.f, 0.5f, 1.f, 1.5f, 2.f, 3.f, 4.f, 6.f};
  float v = mag[c & 7];
  return (c & 8) ? -v : v;
}

// ---------------- workspace layout (bytes) ---------------------------------
static constexpr size_t OFF_LIN  = 0;                          // 16384 f32
static constexpr size_t OFF_PART = 65536;                      // 4096 f32
static constexpr size_t OFF_S    = 81920;                      // 1 f32
static constexpr size_t OFF_EMB  = 131072;                     // B*512 fp4 = 4 MB
static constexpr size_t OFF_H1   = OFF_EMB + 4194304ull;       // B*2048 fp4 = 16 MB
static constexpr size_t OFF_H2   = OFF_H1 + 16777216ull;       // B*1024 fp4 = 8 MB
static constexpr size_t OFF_H3   = OFF_H2 + 8388608ull;        // B*512 fp4 = 4 MB
static constexpr size_t OFF_W1T  = OFF_H3 + 4194304ull;        // 2048*512/2
static constexpr size_t OFF_W2T  = OFF_W1T + 524288ull;        // 1024*2048/2
static constexpr size_t OFF_W3T  = OFF_W2T + 1048576ull;       // 512*1024/2

// ---------------- Stage 1: all 3 transposes, f32 -> fp4 (x128 pre-scale) ---
__global__ void transpose_cvt_all(const float* __restrict__ W1,
                                  const float* __restrict__ W2,
                                  const float* __restrict__ W3,
                                  uint8_t* __restrict__ W1T,
                                  uint8_t* __restrict__ W2T,
                                  uint8_t* __restrict__ W3T) {
  __shared__ float tile[32][33];
  int b = blockIdx.x;
  const float* W;
  uint8_t* WT;
  int K, N, bx, by;
  if (b < 1024) {        // W1: K=512, N=2048 -> 64 x 16 tiles
    W = W1; WT = W1T; K = 512; N = 2048; bx = b & 63; by = b >> 6;
  } else if (b < 3072) { // W2: K=2048, N=1024 -> 32 x 64 tiles
    int t = b - 1024;
    W = W2; WT = W2T; K = 2048; N = 1024; bx = t & 31; by = t >> 5;
  } else {               // W3: K=1024, N=512 -> 16 x 32 tiles
    int t = b - 3072;
    W = W3; WT = W3T; K = 1024; N = 512; bx = t & 15; by = t >> 4;
  }
  int tx = threadIdx.x, ty = threadIdx.y;
  int n0 = bx * 32, k0 = by * 32;
#pragma unroll
  for (int i = ty; i < 32; i += 8)
    tile[i][tx] = W[(size_t)(k0 + i) * N + n0 + tx];
  __syncthreads();
  if (tx < 16) {
#pragma unroll
    for (int i = ty; i < 32; i += 8) {
      // WT row n0+i, k-pair (k0+2tx, k0+2tx+1); pre-scale 2^7 (MX descale 2^-7)
      uint32_t lo = f2fp4(tile[2 * tx][i] * 128.f);
      uint32_t hi = f2fp4(tile[2 * tx + 1][i] * 128.f);
      WT[(size_t)(n0 + i) * (K >> 1) + (k0 >> 1) + tx] = (uint8_t)(lo | (hi << 4));
    }
  }
}

// ---------------- Stage 2: gather + FM ------------------------------------
// One wave per sample. Lane l: field f = l>>4, 8 dims at (l&15)*8.
__global__ void gather_fm(const float* __restrict__ x,
                          const float* __restrict__ fc,
                          const float* __restrict__ emb,
                          uint8_t* __restrict__ ebf,
                          float* __restrict__ lin,
                          float* __restrict__ partials) {
  int tid = threadIdx.x;
  int wv = tid >> 6, lane = tid & 63;
  int b = blockIdx.x * 4 + wv;
  int f = lane >> 4;
  int idx = (int)x[b * 4 + f];                 // raw index (NO offset) for emb
  const float* row = emb + (size_t)idx * 128 + (lane & 15) * 8;
  float4 v0 = ((const float4*)row)[0];
  float4 v1 = ((const float4*)row)[1];
  float s = v0.x + v0.y + v0.z + v0.w + v1.x + v1.y + v1.z + v1.w;
  float q = v0.x * v0.x + v0.y * v0.y + v0.z * v0.z + v0.w * v0.w +
            v1.x * v1.x + v1.y * v1.y + v1.z * v1.z + v1.w * v1.w;

  float vv[8] = {v0.x, v0.y, v0.z, v0.w, v1.x, v1.y, v1.z, v1.w};
  uint32_t pk = 0;
#pragma unroll
  for (int j = 0; j < 8; ++j) pk |= f2fp4(vv[j]) << (4 * j);
  *(uint32_t*)(ebf + (size_t)b * 256 + lane * 4) = pk;   // 4 B/lane coalesced

  float lp = 0.f;
  if ((lane & 15) == 0) {                      // fc lookup USES offsets
    int off = (f == 1) ? 31360 : (f == 2) ? 38167 : (f == 3) ? 38185 : 0;
    lp = fc[idx + off];
  }
#pragma unroll
  for (int m = 32; m; m >>= 1) {
    s += __shfl_xor(s, m);
    q += __shfl_xor(q, m);
    lp += __shfl_xor(lp, m);
  }
  __shared__ float pt[4];
  if (lane == 0) {
    lin[b] = lp;
    pt[wv] = s * s - q;                        // per-sample FM term
  }
  __syncthreads();
  if (tid == 0) partials[blockIdx.x] = pt[0] + pt[1] + pt[2] + pt[3];
}

// ---------------- Stage 3: reduce FM partials -> scalar S ------------------
__global__ void reduce_partials(const float* __restrict__ p,
                                float* __restrict__ S) {
  int tid = threadIdx.x;
  float v = 0.f;
  for (int i = tid; i < 4096; i += 256) v += p[i];
#pragma unroll
  for (int m = 32; m; m >>= 1) v += __shfl_xor(v, m);
  __shared__ float ps[4];
  if ((tid & 63) == 0) ps[tid >> 6] = v;
  __syncthreads();
  if (tid == 0) S[0] = ps[0] + ps[1] + ps[2] + ps[3];
}

// ---------------- Stage 4: MX-fp4 GEMM, C = relu(A*B + bias), B as B^T -----
// 128x128 tile, BK=256 elems (128 B LDS rows), 4 waves of 64x64,
// global_load_lds width=16, chunk swizzle c^=row&7 (R2/R3-verified form),
// MFMA 16x16x128 f8f6f4 fmt=4, scale_a=1 (0x7F), scale_b=2^-7 (0x78).
// 1-D grid GX*128, XCD swizzle: same-A-strip blocks share bid%8 (same XCD).
// K,N in elements; A,BT,C fp4-packed, strides K/2,K/2,N/2 bytes. GX = N/128.
__global__ __launch_bounds__(256) void gemm_fp4_relu(
    const uint8_t* __restrict__ A, const uint8_t* __restrict__ BT,
    const float* __restrict__ bias, uint8_t* __restrict__ C, int K, int N,
    int GX) {
  __shared__ __align__(16) uint8_t As[128][128];
  __shared__ __align__(16) uint8_t Bs[128][128];
  int bid = blockIdx.x;
  // XCD swizzle: by = (bid&7) + 8*(bid/(8*GX)), bx = (bid>>3)&(GX-1)
  int by = (bid & 7) + ((bid >> 3) / GX) * 8;
  int bx = (bid >> 3) & (GX - 1);
  int tid = threadIdx.x;
  int wv = tid >> 6, lane = tid & 63;
  int m0 = by * 128, n0 = bx * 128;
  int mw = (wv >> 1) * 64, nw = (wv & 1) * 64;
  int ml = lane & 15, kg = lane >> 4;
  int Kb = K >> 1;
  int srow = lane >> 3;                        // staging row within 8-row grp
  int scol = ((lane & 7) ^ srow) * 16;         // swizzled source chunk

  f32x4 acc[4][4];
#pragma unroll
  for (int i = 0; i < 4; ++i)
#pragma unroll
    for (int j = 0; j < 4; ++j) acc[i][j] = (f32x4){0.f, 0.f, 0.f, 0.f};

  for (int kt = 0; kt < Kb; kt += 128) {       // 128 B = 256 k-elems
#pragma unroll
    for (int r = 0; r < 4; ++r) {
      int g = r * 4 + wv;                      // 8-row group 0..15
      const uint8_t* ga = A + (size_t)(m0 + 8 * g + srow) * Kb + kt + scol;
      GLOAD16(ga, &As[8 * g][0]);
      const uint8_t* gb = BT + (size_t)(n0 + 8 * g + srow) * Kb + kt + scol;
      GLOAD16(gb, &Bs[8 * g][0]);
    }
    __syncthreads();

    i32x4 z = (i32x4){0, 0, 0, 0};
#pragma unroll
    for (int j = 0; j < 2; ++j) {              // two 128-elem halves
      int p = ((j * 4 + kg) ^ (ml & 7)) * 16;
      i32x8 af[4], bfr[4];
#pragma unroll
      for (int t = 0; t < 4; ++t) {
        i32x4 va = *(const i32x4*)&As[mw + t * 16 + ml][p];
        af[t] = __builtin_shufflevector(va, z, 0, 1, 2, 3, 4, 5, 6, 7);
        i32x4 vb = *(const i32x4*)&Bs[nw + t * 16 + ml][p];
        bfr[t] = __builtin_shufflevector(vb, z, 0, 1, 2, 3, 4, 5, 6, 7);
      }
#pragma unroll
      for (int mt = 0; mt < 4; ++mt)
#pragma unroll
        for (int nt = 0; nt < 4; ++nt)
          acc[mt][nt] = __builtin_amdgcn_mfma_scale_f32_16x16x128_f8f6f4(
              af[mt], bfr[nt], acc[mt][nt],
              /*cbsz=fp4*/ 4, /*blgp=fp4*/ 4,
              0, 0x7F7F7F7F,      // scale_a = 1.0
              0, 0x78787878);     // scale_b = 2^-7 (undo W pre-scale)
    }
    __syncthreads();
  }

  // Epilogue: C/D layout col=lane&15, row=(lane>>4)*4+reg. Pack col pairs
  // (lanes ml, ml^1 hold adjacent cols) via shfl; even lanes store bytes.
  int rbase = kg * 4;
#pragma unroll
  for (int nt = 0; nt < 4; ++nt) {
    int col = n0 + nw + nt * 16 + ml;
    float bv = bias[col];
#pragma unroll
    for (int mt = 0; mt < 4; ++mt) {
      int row = m0 + mw + mt * 16 + rbase;
#pragma unroll
      for (int r = 0; r < 4; ++r) {
        float v = acc[mt][nt][r] + bv;
        v = v > 0.f ? v : 0.f;
        uint32_t code = f2fp4(v);
        uint32_t up = (uint32_t)__shfl_xor((int)code, 1);
        if (!(ml & 1))
          C[(size_t)(row + r) * (N >> 1) + (col >> 1)] =
              (uint8_t)(code | (up << 4));
      }
    }
  }
}

// ---------------- Stage 5: L4 (512->1) + sigmoid ---------------------------
__global__ void mlp_out_sigmoid(const uint8_t* __restrict__ h3,
                                const float* __restrict__ W4,
                                const float* __restrict__ b4,
                                const float* __restrict__ bias,
                                const float* __restrict__ lin,
                                const float* __restrict__ S,
                                float* __restrict__ out) {
  int tid = threadIdx.x;
  int wv = tid >> 6, lane = tid & 63;
  int b = blockIdx.x * 4 + wv;
  uint32_t pk = *(const uint32_t*)(h3 + (size_t)b * 256 + lane * 4);
  const float* wp = W4 + lane * 8;
  float4 w0 = ((const float4*)wp)[0];
  float4 w1 = ((const float4*)wp)[1];
  float wf[8] = {w0.x, w0.y, w0.z, w0.w, w1.x, w1.y, w1.z, w1.w};
  float acc = 0.f;
#pragma unroll
  for (int j = 0; j < 8; ++j)
    acc += fp42f((pk >> (4 * j)) & 15) * wf[j];
#pragma unroll
  for (int m = 32; m; m >>= 1) acc += __shfl_xor(acc, m);
  if (lane == 0) {
    float z = acc + b4[0] + bias[0] + lin[b] + 0.5f * S[0];
    out[b] = 1.f / (1.f + expf(-z));
  }
}

// ---------------------------------------------------------------------------
extern "C" void kernel_launch(void* const* d_in, const int* in_sizes, int n_in,
                              void* d_out, int out_size, void* d_ws,
                              size_t ws_size, hipStream_t stream) {
  const float* x    = (const float*)d_in[0];
  const float* bias = (const float*)d_in[1];
  const float* fc   = (const float*)d_in[2];
  const float* emb  = (const float*)d_in[3];
  const float* W1   = (const float*)d_in[4];
  const float* b1   = (const float*)d_in[5];
  const float* W2   = (const float*)d_in[6];
  const float* b2   = (const float*)d_in[7];
  const float* W3   = (const float*)d_in[8];
  const float* b3   = (const float*)d_in[9];
  const float* W4   = (const float*)d_in[10];
  const float* b4   = (const float*)d_in[11];
  float* out = (float*)d_out;

  char* ws = (char*)d_ws;
  float* lin    = (float*)(ws + OFF_LIN);
  float* part   = (float*)(ws + OFF_PART);
  float* Sp     = (float*)(ws + OFF_S);
  uint8_t* EMBb = (uint8_t*)(ws + OFF_EMB);
  uint8_t* H1   = (uint8_t*)(ws + OFF_H1);
  uint8_t* H2   = (uint8_t*)(ws + OFF_H2);
  uint8_t* H3   = (uint8_t*)(ws + OFF_H3);
  uint8_t* W1T  = (uint8_t*)(ws + OFF_W1T);
  uint8_t* W2T  = (uint8_t*)(ws + OFF_W2T);
  uint8_t* W3T  = (uint8_t*)(ws + OFF_W3T);

  transpose_cvt_all<<<3584, dim3(32, 8), 0, stream>>>(W1, W2, W3, W1T, W2T,
                                                      W3T);
  gather_fm<<<4096, 256, 0, stream>>>(x, fc, emb, EMBb, lin, part);
  reduce_partials<<<1, 256, 0, stream>>>(part, Sp);

  gemm_fp4_relu<<<2048, 256, 0, stream>>>(EMBb, W1T, b1, H1, 512, 2048, 16);
  gemm_fp4_relu<<<1024, 256, 0, stream>>>(H1, W2T, b2, H2, 2048, 1024, 8);
  gemm_fp4_relu<<<512, 256, 0, stream>>>(H2, W3T, b3, H3, 1024, 512, 4);

  mlp_out_sigmoid<<<4096, 256, 0, stream>>>(H3, W4, b4, bias, lin, Sp, out);
}

// Round 7
// 181.008 us; speedup vs baseline: 4.4213x; 1.1427x over previous
//
#include <hip/hip_runtime.h>
#include <hip/hip_fp8.h>
#include <cstdint>

// ---------------------------------------------------------------------------
// DeepFM forward, MI355X (R7).
//   Stage 1: prep — W1..W3 f32->fp4 W^T (pre-scaled 2^7)  +  gather: embed_x
//            fp8 (B,512), per-sample lin, FM partials    [one fused kernel]
//   Stage 2: reduce — batch-global FM scalar S (fp32, reference quirk)
//   Stage 3: 3x mixed MFMA GEMM: A=fp8 activations, B=fp4 weights
//            (mfma_scale 16x16x128 f8f6f4, cbsz=0/blgp=4), bias+ReLU, fp8 out
//   Stage 4: L4 dot (512->1, fp32 weights) + sigmoid(fm + mlp)
//
// R7 changes vs R6 (R6: FETCH solved 66.7->4.3 MB via XCD swizzle, but GEMM1
// VALU-bound: VALUBusy 37% ~= 64 software f2fp4 encodes/lane in epilogue):
//  - Activations fp8 end-to-end; weights stay fp4 (pre-scale 2^7, MX
//    scale_b=2^-7). Epilogue: HW v_cvt_pk_fp8_f32, byte stores (~5x less VALU).
//  - A LDS tile 128x256B, 16-chunk XOR swizzle (2 lanes/bank = free);
//    B side byte-identical to R6 (measured 0 conflicts).
//  - transpose+gather fused into one prep kernel (7 graph nodes).
// ---------------------------------------------------------------------------

typedef float f32x4 __attribute__((ext_vector_type(4)));
typedef int i32x4 __attribute__((ext_vector_type(4)));
typedef int i32x8 __attribute__((ext_vector_type(8)));

#define GLOAD16(gptr, lptr)                                                \
  __builtin_amdgcn_global_load_lds(                                        \
      (const __attribute__((address_space(1))) void*)(gptr),               \
      (__attribute__((address_space(3))) void*)(lptr), 16, 0, 0)

// fp4 e2m1 encode (weights only; RNE; magnitudes 0,.5,1,1.5,2,3,4,6)
__device__ inline uint32_t f2fp4(float v) {
  uint32_t s = (__float_as_uint(v) >> 31) << 3;
  float a = fabsf(v);
  uint32_t m;
  if (a < 0.25f) m = 0;
  else if (a < 0.75f) m = 1;
  else if (a < 1.25f) m = 2;
  else if (a < 1.75f) m = 3;
  else if (a < 2.5f)  m = 4;
  else if (a < 3.5f)  m = 5;
  else if (a < 5.0f)  m = 6;
  else m = 7;
  return s | m;
}
__device__ inline float fp82f(uint8_t b) {
  __hip_fp8_e4m3 t;
  t.__x = b;
  return (float)t;
}

// ---------------- workspace layout (bytes) ---------------------------------
static constexpr size_t OFF_LIN  = 0;                          // 16384 f32
static constexpr size_t OFF_PART = 65536;                      // 4096 f32
static constexpr size_t OFF_S    = 81920;                      // 1 f32
static constexpr size_t OFF_EMB  = 131072;                     // B*512 fp8
static constexpr size_t OFF_H1   = OFF_EMB + 8388608ull;       // B*2048 fp8
static constexpr size_t OFF_H2   = OFF_H1 + 33554432ull;       // B*1024 fp8
static constexpr size_t OFF_H3   = OFF_H2 + 16777216ull;       // B*512 fp8
static constexpr size_t OFF_W1T  = OFF_H3 + 8388608ull;        // 2048*512 fp4
static constexpr size_t OFF_W2T  = OFF_W1T + 524288ull;        // 1024*2048 fp4
static constexpr size_t OFF_W3T  = OFF_W2T + 1048576ull;       // 512*1024 fp4

// ---------------- Stage 1: fused prep (transposes + gather) ----------------
// Blocks 0..3583: weight transpose f32 -> fp4 W^T (x128 pre-scale).
// Blocks 3584..7679: gather 4 samples/block (1/wave), fp8 embed + lin + FM.
__global__ void prep(const float* __restrict__ W1, const float* __restrict__ W2,
                     const float* __restrict__ W3, uint8_t* __restrict__ W1T,
                     uint8_t* __restrict__ W2T, uint8_t* __restrict__ W3T,
                     const float* __restrict__ x, const float* __restrict__ fc,
                     const float* __restrict__ emb, uint8_t* __restrict__ ebf,
                     float* __restrict__ lin, float* __restrict__ partials) {
  __shared__ __align__(16) float smem[32 * 33];
  int blk = blockIdx.x;
  int tid = threadIdx.x;
  if (blk < 3584) {  // ---- transpose ----
    const float* W;
    uint8_t* WT;
    int K, N, bx, by;
    if (blk < 1024) {        // W1: K=512, N=2048
      W = W1; WT = W1T; K = 512; N = 2048; bx = blk & 63; by = blk >> 6;
    } else if (blk < 3072) { // W2: K=2048, N=1024
      int t = blk - 1024;
      W = W2; WT = W2T; K = 2048; N = 1024; bx = t & 31; by = t >> 5;
    } else {                 // W3: K=1024, N=512
      int t = blk - 3072;
      W = W3; WT = W3T; K = 1024; N = 512; bx = t & 15; by = t >> 4;
    }
    int tx = tid & 31, ty = tid >> 5;
    int n0 = bx * 32, k0 = by * 32;
#pragma unroll
    for (int i = ty; i < 32; i += 8)
      smem[i * 33 + tx] = W[(size_t)(k0 + i) * N + n0 + tx];
    __syncthreads();
    if (tx < 16) {
#pragma unroll
      for (int i = ty; i < 32; i += 8) {
        uint32_t lo = f2fp4(smem[(2 * tx) * 33 + i] * 128.f);
        uint32_t hi = f2fp4(smem[(2 * tx + 1) * 33 + i] * 128.f);
        WT[(size_t)(n0 + i) * (K >> 1) + (k0 >> 1) + tx] =
            (uint8_t)(lo | (hi << 4));
      }
    }
  } else {  // ---- gather ----
    int gb = blk - 3584;
    int wv = tid >> 6, lane = tid & 63;
    int b = gb * 4 + wv;
    int f = lane >> 4;
    int idx = (int)x[b * 4 + f];               // raw index (NO offset) for emb
    const float* row = emb + (size_t)idx * 128 + (lane & 15) * 8;
    float4 v0 = ((const float4*)row)[0];
    float4 v1 = ((const float4*)row)[1];
    float s = v0.x + v0.y + v0.z + v0.w + v1.x + v1.y + v1.z + v1.w;
    float q = v0.x * v0.x + v0.y * v0.y + v0.z * v0.z + v0.w * v0.w +
              v1.x * v1.x + v1.y * v1.y + v1.z * v1.z + v1.w * v1.w;

    int lo = 0, hi = 0;
    lo = __builtin_amdgcn_cvt_pk_fp8_f32(v0.x, v0.y, lo, false);
    lo = __builtin_amdgcn_cvt_pk_fp8_f32(v0.z, v0.w, lo, true);
    hi = __builtin_amdgcn_cvt_pk_fp8_f32(v1.x, v1.y, hi, false);
    hi = __builtin_amdgcn_cvt_pk_fp8_f32(v1.z, v1.w, hi, true);
    int2 pk = make_int2(lo, hi);
    *(int2*)(ebf + (size_t)b * 512 + lane * 8) = pk;   // 8 B/lane coalesced

    float lp = 0.f;
    if ((lane & 15) == 0) {                    // fc lookup USES offsets
      int off = (f == 1) ? 31360 : (f == 2) ? 38167 : (f == 3) ? 38185 : 0;
      lp = fc[idx + off];
    }
#pragma unroll
    for (int m = 32; m; m >>= 1) {
      s += __shfl_xor(s, m);
      q += __shfl_xor(q, m);
      lp += __shfl_xor(lp, m);
    }
    float* pt = smem;
    if (lane == 0) {
      lin[b] = lp;
      pt[wv] = s * s - q;                      // per-sample FM term
    }
    __syncthreads();
    if (tid == 0) partials[gb] = pt[0] + pt[1] + pt[2] + pt[3];
  }
}

// ---------------- Stage 2: reduce FM partials -> scalar S ------------------
__global__ void reduce_partials(const float* __restrict__ p,
                                float* __restrict__ S) {
  int tid = threadIdx.x;
  float v = 0.f;
  for (int i = tid; i < 4096; i += 256) v += p[i];
#pragma unroll
  for (int m = 32; m; m >>= 1) v += __shfl_xor(v, m);
  __shared__ float ps[4];
  if ((tid & 63) == 0) ps[tid >> 6] = v;
  __syncthreads();
  if (tid == 0) S[0] = ps[0] + ps[1] + ps[2] + ps[3];
}

// ---------------- Stage 3: mixed GEMM, C = relu(A*B + bias) ----------------
// A fp8 (stride K B), BT fp4 (stride K/2 B), C fp8 (stride N B).
// 128x128 tile, BK=256 elems. A LDS rows 256 B (16-chunk XOR swizzle),
// B LDS rows 128 B (R6-verified swizzle, 0 conflicts). 4 waves of 64x64.
// MFMA 16x16x128 f8f6f4: cbsz=0 (fp8 A), blgp=4 (fp4 B),
// scale_a=1 (0x7F), scale_b=2^-7 (0x78, undoes W pre-scale).
// 1-D grid, XCD swizzle: same-A-strip blocks share bid%8. GX = N/128.
__global__ __launch_bounds__(256) void gemm_mx_relu(
    const uint8_t* __restrict__ A, const uint8_t* __restrict__ BT,
    const float* __restrict__ bias, uint8_t* __restrict__ C, int K, int N,
    int GX) {
  __shared__ __align__(16) uint8_t As[128][256];   // 32 KB
  __shared__ __align__(16) uint8_t Bs[128][128];   // 16 KB
  int bid = blockIdx.x;
  int by = (bid & 7) + ((bid >> 3) / GX) * 8;
  int bx = (bid >> 3) & (GX - 1);
  int tid = threadIdx.x;
  int wv = tid >> 6, lane = tid & 63;
  int m0 = by * 128, n0 = bx * 128;
  int mw = (wv >> 1) * 64, nw = (wv & 1) * 64;
  int ml = lane & 15, kg = lane >> 4;
  int Kb2 = K >> 1;
  // A staging: 4 rows per GLOAD16 (64 lanes x 16B = 1024 B)
  int arow = lane >> 4;                        // row within 4-row group
  // B staging: 8 rows per GLOAD16
  int brow = lane >> 3;
  int bcol = ((lane & 7) ^ brow) * 16;

  f32x4 acc[4][4];
#pragma unroll
  for (int i = 0; i < 4; ++i)
#pragma unroll
    for (int j = 0; j < 4; ++j) acc[i][j] = (f32x4){0.f, 0.f, 0.f, 0.f};

  for (int kt = 0; kt < K; kt += 256) {
#pragma unroll
    for (int r = 0; r < 8; ++r) {              // A: 32 groups of 4 rows
      int g = r * 4 + wv;
      int trow = 4 * g + arow;
      int acol = ((lane & 15) ^ (trow & 15)) * 16;
      const uint8_t* ga = A + (size_t)(m0 + trow) * K + kt + acol;
      GLOAD16(ga, &As[4 * g][0]);
    }
#pragma unroll
    for (int r = 0; r < 4; ++r) {              // B: 16 groups of 8 rows
      int g = r * 4 + wv;
      const uint8_t* gb =
          BT + (size_t)(n0 + 8 * g + brow) * Kb2 + (kt >> 1) + bcol;
      GLOAD16(gb, &Bs[8 * g][0]);
    }
    __syncthreads();

    i32x4 z = (i32x4){0, 0, 0, 0};
#pragma unroll
    for (int j = 0; j < 2; ++j) {              // two 128-elem k-halves
      int c0 = 8 * j + 2 * kg;                 // A chunks (of 16)
      int pa0 = (c0 ^ ml) * 16;
      int pa1 = ((c0 + 1) ^ ml) * 16;
      int pb = ((4 * j + kg) ^ (ml & 7)) * 16; // B chunk (of 8)
      i32x8 af[4], bfr[4];
#pragma unroll
      for (int t = 0; t < 4; ++t) {
        int ra = mw + t * 16 + ml;
        i32x4 a0 = *(const i32x4*)&As[ra][pa0];
        i32x4 a1 = *(const i32x4*)&As[ra][pa1];
        af[t] = __builtin_shufflevector(a0, a1, 0, 1, 2, 3, 4, 5, 6, 7);
        i32x4 vb = *(const i32x4*)&Bs[nw + t * 16 + ml][pb];
        bfr[t] = __builtin_shufflevector(vb, z, 0, 1, 2, 3, 4, 5, 6, 7);
      }
#pragma unroll
      for (int mt = 0; mt < 4; ++mt)
#pragma unroll
        for (int nt = 0; nt < 4; ++nt)
          acc[mt][nt] = __builtin_amdgcn_mfma_scale_f32_16x16x128_f8f6f4(
              af[mt], bfr[nt], acc[mt][nt],
              /*cbsz=fp8*/ 0, /*blgp=fp4*/ 4,
              0, 0x7F7F7F7F,      // scale_a = 1.0
              0, 0x78787878);     // scale_b = 2^-7
    }
    __syncthreads();
  }

  // Epilogue: C/D layout col=lane&15, row=(lane>>4)*4+reg.
  // HW packed fp8 convert, byte stores.
  int rbase = kg * 4;
#pragma unroll
  for (int nt = 0; nt < 4; ++nt) {
    int col = n0 + nw + nt * 16 + ml;
    float bv = bias[col];
#pragma unroll
    for (int mt = 0; mt < 4; ++mt) {
      int row = m0 + mw + mt * 16 + rbase;
      float v0 = acc[mt][nt][0] + bv, v1 = acc[mt][nt][1] + bv;
      float v2 = acc[mt][nt][2] + bv, v3 = acc[mt][nt][3] + bv;
      v0 = v0 > 0.f ? v0 : 0.f;
      v1 = v1 > 0.f ? v1 : 0.f;
      v2 = v2 > 0.f ? v2 : 0.f;
      v3 = v3 > 0.f ? v3 : 0.f;
      int w01 = __builtin_amdgcn_cvt_pk_fp8_f32(v0, v1, 0, false);
      int w23 = __builtin_amdgcn_cvt_pk_fp8_f32(v2, v3, 0, false);
      C[(size_t)(row + 0) * N + col] = (uint8_t)(w01 & 0xFF);
      C[(size_t)(row + 1) * N + col] = (uint8_t)((w01 >> 8) & 0xFF);
      C[(size_t)(row + 2) * N + col] = (uint8_t)(w23 & 0xFF);
      C[(size_t)(row + 3) * N + col] = (uint8_t)((w23 >> 8) & 0xFF);
    }
  }
}

// ---------------- Stage 4: L4 (512->1) + sigmoid ---------------------------
__global__ void mlp_out_sigmoid(const uint8_t* __restrict__ h3,
                                const float* __restrict__ W4,
                                const float* __restrict__ b4,
                                const float* __restrict__ bias,
                                const float* __restrict__ lin,
                                const float* __restrict__ S,
                                float* __restrict__ out) {
  int tid = threadIdx.x;
  int wv = tid >> 6, lane = tid & 63;
  int b = blockIdx.x * 4 + wv;
  uint64_t pk = *(const uint64_t*)(h3 + (size_t)b * 512 + lane * 8);
  const float* wp = W4 + lane * 8;
  float4 w0 = ((const float4*)wp)[0];
  float4 w1 = ((const float4*)wp)[1];
  float wf[8] = {w0.x, w0.y, w0.z, w0.w, w1.x, w1.y, w1.z, w1.w};
  float acc = 0.f;
#pragma unroll
  for (int j = 0; j < 8; ++j)
    acc += fp82f((uint8_t)(pk >> (8 * j))) * wf[j];
#pragma unroll
  for (int m = 32; m; m >>= 1) acc += __shfl_xor(acc, m);
  if (lane == 0) {
    float z = acc + b4[0] + bias[0] + lin[b] + 0.5f * S[0];
    out[b] = 1.f / (1.f + expf(-z));
  }
}

// ---------------------------------------------------------------------------
extern "C" void kernel_launch(void* const* d_in, const int* in_sizes, int n_in,
                              void* d_out, int out_size, void* d_ws,
                              size_t ws_size, hipStream_t stream) {
  const float* x    = (const float*)d_in[0];
  const float* bias = (const float*)d_in[1];
  const float* fc   = (const float*)d_in[2];
  const float* emb  = (const float*)d_in[3];
  const float* W1   = (const float*)d_in[4];
  const float* b1   = (const float*)d_in[5];
  const float* W2   = (const float*)d_in[6];
  const float* b2   = (const float*)d_in[7];
  const float* W3   = (const float*)d_in[8];
  const float* b3   = (const float*)d_in[9];
  const float* W4   = (const float*)d_in[10];
  const float* b4   = (const float*)d_in[11];
  float* out = (float*)d_out;

  char* ws = (char*)d_ws;
  float* lin    = (float*)(ws + OFF_LIN);
  float* part   = (float*)(ws + OFF_PART);
  float* Sp     = (float*)(ws + OFF_S);
  uint8_t* EMBb = (uint8_t*)(ws + OFF_EMB);
  uint8_t* H1   = (uint8_t*)(ws + OFF_H1);
  uint8_t* H2   = (uint8_t*)(ws + OFF_H2);
  uint8_t* H3   = (uint8_t*)(ws + OFF_H3);
  uint8_t* W1T  = (uint8_t*)(ws + OFF_W1T);
  uint8_t* W2T  = (uint8_t*)(ws + OFF_W2T);
  uint8_t* W3T  = (uint8_t*)(ws + OFF_W3T);

  prep<<<7680, 256, 0, stream>>>(W1, W2, W3, W1T, W2T, W3T, x, fc, emb, EMBb,
                                 lin, part);
  reduce_partials<<<1, 256, 0, stream>>>(part, Sp);

  gemm_mx_relu<<<2048, 256, 0, stream>>>(EMBb, W1T, b1, H1, 512, 2048, 16);
  gemm_mx_relu<<<1024, 256, 0, stream>>>(H1, W2T, b2, H2, 2048, 1024, 8);
  gemm_mx_relu<<<512, 256, 0, stream>>>(H2, W3T, b3, H3, 1024, 512, 4);

  mlp_out_sigmoid<<<4096, 256, 0, stream>>>(H3, W4, b4, bias, lin, Sp, out);
}